// Round 1
// baseline (565.837 us; speedup 1.0000x reference)
//
#include <hip/hip_runtime.h>

// BoneLengthLoss: masked MSE over 32 bone lengths, B=524288, 37 kpts, fp32.
// Memory-bound streaming reduction: ~485 MB must cross HBM -> floor ~77us.

#define NBONES  32
#define NKPT    37
#define ROWF    (NKPT * 3)       // 111 floats per pose row (444 B)
#define NB      32               // batch rows per LDS tile (32*444 B, 16B-aligned)
#define BLOCK   256
#define TILE_F  (NB * ROWF)      // 3552 floats
#define TILE_V4 (TILE_F / 4)     // 888 float4
#define TILE_M  (NB * NKPT)      // 1184 mask bytes per tile
#define TILE_MW (TILE_M / 4)     // 296 words

__constant__ unsigned char c_j1[NBONES] = {1,1,1,2,3,11,11,12,13,14,15,16,12,18,20,13,19,21,16,16,24,25,24,27,29,25,28,30,17,33,34,35};
__constant__ unsigned char c_j2[NBONES] = {2,3,4,5,6,12,13,14,14,15,16,17,18,20,22,19,21,23,24,25,26,26,27,29,31,28,30,32,33,34,35,36};

// valid_mask is jnp.bool_: harness may ship 1 byte/elem (numpy bool) or 4
// bytes/elem (int32). Detect: scan first n_mask BYTES (safe under both
// layouts). If any byte at index %4 != 0 is nonzero -> byte layout (random
// 0/1 mask guarantees hits). If all such bytes are 0 -> int32 layout
// (little-endian 0/1 values have zero upper bytes). Flag lands in ws[2].
__global__ void detect_mask_layout(const unsigned int* __restrict__ mw, int nwords,
                                   unsigned int* __restrict__ ws) {
    unsigned int local = 0;
    for (int i = blockIdx.x * blockDim.x + threadIdx.x; i < nwords;
         i += gridDim.x * blockDim.x)
        local |= mw[i] & 0xFFFFFF00u;
    if (__any(local != 0) && (threadIdx.x & 63) == 0)
        atomicOr(&ws[2], 1u);
}

// ws layout: ws[0] = num (float, atomicAdd), ws[1] = den (uint, exact),
//            ws[2] = mask-layout flag (nonzero => byte layout)
__global__ __launch_bounds__(BLOCK, 4)
void bone_main(const float* __restrict__ pred, const float* __restrict__ ref,
               const void* __restrict__ mask, int B, unsigned int* __restrict__ ws) {
    __shared__ float4 s_pred[TILE_V4];
    __shared__ float4 s_ref[TILE_V4];
    __shared__ unsigned int s_mask_w[TILE_MW];
    __shared__ float s_rednum[BLOCK / 64];
    __shared__ unsigned int s_redden[BLOCK / 64];

    const int tid  = threadIdx.x;
    const int lrow = tid >> 3;   // 0..31: which batch row of the tile
    const int grp  = tid & 7;    // 0..7 : which group of 4 bones

    const bool mask_bytes = (ws[2] != 0);

    // Hoist this thread's bone endpoints into registers (loaded once).
    int j1v[4], j2v[4];
#pragma unroll
    for (int k = 0; k < 4; ++k) {
        j1v[k] = (int)c_j1[grp * 4 + k] * 3;
        j2v[k] = (int)c_j2[grp * 4 + k] * 3;
    }
    int m1v[4], m2v[4];
#pragma unroll
    for (int k = 0; k < 4; ++k) {
        m1v[k] = (int)c_j1[grp * 4 + k];
        m2v[k] = (int)c_j2[grp * 4 + k];
    }

    const float4* __restrict__ pred4 = (const float4*)pred;
    const float4* __restrict__ ref4  = (const float4*)ref;
    const unsigned int* __restrict__ mw = (const unsigned int*)mask;
    const int* __restrict__ mi = (const int*)mask;

    float num = 0.0f;
    unsigned int den = 0u;

    const int ntiles = B / NB;   // B = 524288 -> 16384 tiles, exact
    for (int tile = blockIdx.x; tile < ntiles; tile += gridDim.x) {
        // ---- stage: flat contiguous float4 copy, fully coalesced ----
        const int base4 = tile * TILE_V4;
#pragma unroll
        for (int it = 0; it < (TILE_V4 + BLOCK - 1) / BLOCK; ++it) {
            int i = tid + it * BLOCK;
            if (i < TILE_V4) {
                s_pred[i] = pred4[base4 + i];
                s_ref[i]  = ref4[base4 + i];
            }
        }
        if (mask_bytes) {
            const int mb = tile * TILE_MW;
            for (int i = tid; i < TILE_MW; i += BLOCK)
                s_mask_w[i] = mw[mb + i];
        } else {
            const int mb = tile * TILE_M;
            unsigned char* sb = (unsigned char*)s_mask_w;
            for (int i = tid; i < TILE_M; i += BLOCK)
                sb[i] = (unsigned char)mi[mb + i];
        }
        __syncthreads();

        // ---- compute: 8 threads/row, 4 bones each ----
        const float* sp = (const float*)s_pred + lrow * ROWF;
        const float* sr = (const float*)s_ref  + lrow * ROWF;
        const unsigned char* sm = (const unsigned char*)s_mask_w + lrow * NKPT;
#pragma unroll
        for (int k = 0; k < 4; ++k) {
            const int a = j1v[k], b = j2v[k];
            float dx = sp[b] - sp[a], dy = sp[b + 1] - sp[a + 1], dz = sp[b + 2] - sp[a + 2];
            float pl = sqrtf(dx * dx + dy * dy + dz * dz);
            float ex = sr[b] - sr[a], ey = sr[b + 1] - sr[a + 1], ez = sr[b + 2] - sr[a + 2];
            float rl = sqrtf(ex * ex + ey * ey + ez * ez);
            unsigned int v = (unsigned int)(sm[m1v[k]] & sm[m2v[k]]);
            float d = pl - rl;
            num += v ? d * d : 0.0f;
            den += v;
        }
        __syncthreads();
    }

    // ---- reduce: wave shuffle -> LDS -> one atomic per block ----
#pragma unroll
    for (int off = 32; off > 0; off >>= 1) {
        num += __shfl_down(num, off, 64);
        den += __shfl_down(den, off, 64);
    }
    const int wave = tid >> 6, lane = tid & 63;
    if (lane == 0) { s_rednum[wave] = num; s_redden[wave] = den; }
    __syncthreads();
    if (tid == 0) {
        float n = 0.0f;
        unsigned int d = 0u;
#pragma unroll
        for (int w = 0; w < BLOCK / 64; ++w) { n += s_rednum[w]; d += s_redden[w]; }
        atomicAdd((float*)&ws[0], n);
        atomicAdd(&ws[1], d);
    }
}

__global__ void finalize(const unsigned int* __restrict__ ws, float* __restrict__ out) {
    out[0] = ((const float*)ws)[0] / (float)ws[1];
}

extern "C" void kernel_launch(void* const* d_in, const int* in_sizes, int n_in,
                              void* d_out, int out_size, void* d_ws, size_t ws_size,
                              hipStream_t stream) {
    const float* pred = (const float*)d_in[0];
    const float* ref  = (const float*)d_in[1];
    const void*  mask = d_in[2];
    const int n_mask  = in_sizes[2];           // 524288 * 37
    const int B       = n_mask / NKPT;
    unsigned int* ws  = (unsigned int*)d_ws;

    hipMemsetAsync(d_ws, 0, 16, stream);       // zero num/den/flag (graph-safe)
    detect_mask_layout<<<256, BLOCK, 0, stream>>>(
        (const unsigned int*)mask, n_mask / 4, ws);
    bone_main<<<2048, BLOCK, 0, stream>>>(pred, ref, mask, B, ws);
    finalize<<<1, 1, 0, stream>>>(ws, (float*)d_out);
}